// Round 2
// baseline (215.083 us; speedup 1.0000x reference)
//
#include <hip/hip_runtime.h>
#include <hip/hip_bf16.h>
#include <stdint.h>

// Problem constants
#define BB 8
#define CC 64
#define NN 16384
#define KNB 8            // neighbors
// Padded GEMM1 K: cols 0..7 = dis[k], cols 8+kk*64+c = feature[c][idx[kk]], 520..543 = 0
#define K1P 544

typedef __attribute__((ext_vector_type(8))) short   s16x8;
typedef __attribute__((ext_vector_type(4))) short   s16x4;
typedef __attribute__((ext_vector_type(8))) __bf16  bf16x8;
typedef __attribute__((ext_vector_type(4))) float   f32x4;

__device__ __forceinline__ unsigned short f2bf(float f) {
    unsigned u = __builtin_bit_cast(unsigned, f);
    u = (u + 0x7FFFu + ((u >> 16) & 1u)) >> 16;   // RNE, inputs finite
    return (unsigned short)u;
}

// ---- workspace layout (bytes) ----
// featT [B][N][64] bf16 : 16,777,216   @ 0
// disB  [B][N][8]  bf16 :  2,097,152   @ 16,777,216
// W1b   [128][544] bf16 :    139,264   @ 18,874,368
// W2b   [128][128] bf16 :     32,768   @ 19,013,632
// W3b   [256][128] bf16 :     65,536   @ 19,046,400   (total ~19.1 MB)
#define OFF_DISB  16777216u
#define OFF_W1B   18874368u
#define OFF_W2B   19013632u
#define OFF_W3B   19046400u

// ---------------- prep: dis->bf16, weights->bf16 (W1 column-permuted + padded) ----------------
// Thread budget: 131072 (dis, 8 elems each) + 69632 (W1b) + 16384 (W2) + 32768 (W3)
//              = 249,856 = 976 blocks * 256
__global__ __launch_bounds__(256) void prep_misc(
    const float* __restrict__ dis, const float* __restrict__ W1,
    const float* __restrict__ W2, const float* __restrict__ W3,
    unsigned short* __restrict__ disB, unsigned short* __restrict__ w1b,
    unsigned short* __restrict__ w2b, unsigned short* __restrict__ w3b)
{
    int tid = blockIdx.x * 256 + threadIdx.x;
    if (tid < 131072) {                        // one POINT per thread: 8 dis values
        const float* dp = dis + (size_t)tid * 8;
        s16x8 pk;
        #pragma unroll
        for (int j = 0; j < 8; ++j) pk[j] = (short)f2bf(dp[j]);
        *(s16x8*)(disB + (size_t)tid * 8) = pk;
    } else {
        int t2 = tid - 131072;
        if (t2 < 69632) {                      // W1b: [128][544] permuted+padded
            int o = t2 / 544, kp = t2 - o * 544;
            float val = 0.f;
            if (kp < 8)        val = W1[o * 520 + kp * 65];            // dis weight of neighbor kp
            else if (kp < 520) {
                int kk = (kp - 8) >> 6, c = (kp - 8) & 63;
                val = W1[o * 520 + kk * 65 + 1 + c];                   // feature weight
            }
            w1b[t2] = f2bf(val);
        } else {
            int t3 = t2 - 69632;
            if (t3 < 16384) w2b[t3] = f2bf(W2[t3]);
            else {
                int t4 = t3 - 16384;
                if (t4 < 32768) w3b[t4] = f2bf(W3[t4]);
            }
        }
    }
}

// ---------------- prep: feature [B][C][N] fp32 -> featT [B][N][C] bf16 ----------------
__global__ __launch_bounds__(256) void prep_featT(
    const float* __restrict__ feat, unsigned short* __restrict__ featT)
{
    int gt = blockIdx.x * 256 + threadIdx.x;   // global point 0..131071
    int b = gt >> 14, n = gt & 16383;
    const float* fp = feat + ((size_t)b << 20) + n;     // b*64*16384
    unsigned short v[64];
    #pragma unroll
    for (int c = 0; c < 64; ++c) v[c] = f2bf(fp[(size_t)c << 14]);  // coalesced across lanes
    unsigned short* dst = featT + (size_t)gt * 64;
    #pragma unroll
    for (int j = 0; j < 8; ++j) {
        s16x8 pk;
        #pragma unroll
        for (int i = 0; i < 8; ++i) pk[i] = (short)v[j * 8 + i];
        *(s16x8*)(dst + j * 8) = pk;
    }
}

// ---------------- main fused kernel ----------------
// Block = 256 thr = 4 waves; each wave owns 16 consecutive points end-to-end (no barriers).
// Orientation: D[ch][pt] = W * X^T  (A = W rows=ch, B = X^T cols=pt) so stores are n-contiguous.
// MFMA 16x16x32 bf16 layout: A[i=lane&15][k=(lane>>4)*8+j], B[k][(lane&15)], D col=lane&15, row=(lane>>4)*4+r.
__global__ __launch_bounds__(256, 4) void pointconv_main(
    const unsigned short* __restrict__ featT,
    const unsigned short* __restrict__ disB,
    const int* __restrict__ idx,
    const unsigned short* __restrict__ w1b,
    const unsigned short* __restrict__ w2b,
    const unsigned short* __restrict__ w3b,
    const float* __restrict__ b1, const float* __restrict__ b2,
    const float* __restrict__ b3, float* __restrict__ out)
{
    __shared__ __align__(16) unsigned short hl[4 * 2 * 16 * 136];  // per-wave H1/H2 strips, stride 136
    const int tid  = threadIdx.x;
    const int wv   = tid >> 6;
    const int lane = tid & 63;
    const int grp  = lane >> 4;
    const int l15  = lane & 15;
    const int p    = blockIdx.x * 64 + wv * 16 + l15;  // this lane's point (B-frag / store role)
    const int b    = p >> 14;
    const int n    = p & 16383;

    unsigned short* H1 = hl + wv * (2 * 16 * 136);
    unsigned short* H2 = H1 + 16 * 136;

    // ================= GEMM1: [128 x 544] * [544 x 16] =================
    f32x4 acc[8];
    #pragma unroll
    for (int t = 0; t < 8; ++t) acc[t] = (f32x4){0.f, 0.f, 0.f, 0.f};

    const size_t featRow = ((size_t)b << 14);
    const int idxBase = p * 8;

    #pragma unroll
    for (int kb = 0; kb < 17; ++kb) {
        const int k = kb * 32 + grp * 8;
        bf16x8 bfrag;
        if (kb == 0 && grp == 0) {
            bfrag = *(const bf16x8*)(disB + (size_t)p * 8);        // 8 dis values
        } else if (k < 520) {
            const int kk = (k - 8) >> 6;
            const int c0 = (k - 8) & 63;
            const int iv = idx[idxBase + kk];                      // neighbor index
            bfrag = *(const bf16x8*)(featT + ((featRow + (size_t)iv) << 6) + c0); // 16B gather
        } else {
            bfrag = __builtin_bit_cast(bf16x8, (s16x8){0,0,0,0,0,0,0,0});
        }
        #pragma unroll
        for (int t = 0; t < 8; ++t) {
            bf16x8 afrag = *(const bf16x8*)(w1b + (t * 16 + l15) * 544 + k);
            acc[t] = __builtin_amdgcn_mfma_f32_16x16x32_bf16(afrag, bfrag, acc[t], 0, 0, 0);
        }
    }
    // epilogue 1: bias + relu -> H1[pt][ch] bf16
    #pragma unroll
    for (int t = 0; t < 8; ++t) {
        const int chb = t * 16 + grp * 4;
        s16x4 pk;
        #pragma unroll
        for (int r = 0; r < 4; ++r) {
            float v = acc[t][r] + b1[chb + r];
            pk[r] = (short)f2bf(v > 0.f ? v : 0.f);
        }
        *(s16x4*)(H1 + l15 * 136 + chb) = pk;
    }

    // ================= GEMM2: [128 x 128] * [128 x 16] =================
    f32x4 acc2[8];
    #pragma unroll
    for (int t = 0; t < 8; ++t) acc2[t] = (f32x4){0.f, 0.f, 0.f, 0.f};
    #pragma unroll
    for (int kb = 0; kb < 4; ++kb) {
        const int k = kb * 32 + grp * 8;
        bf16x8 bfrag = *(const bf16x8*)(H1 + l15 * 136 + k);
        #pragma unroll
        for (int t = 0; t < 8; ++t) {
            bf16x8 afrag = *(const bf16x8*)(w2b + (t * 16 + l15) * 128 + k);
            acc2[t] = __builtin_amdgcn_mfma_f32_16x16x32_bf16(afrag, bfrag, acc2[t], 0, 0, 0);
        }
    }
    #pragma unroll
    for (int t = 0; t < 8; ++t) {
        const int chb = t * 16 + grp * 4;
        s16x4 pk;
        #pragma unroll
        for (int r = 0; r < 4; ++r) {
            float v = acc2[t][r] + b2[chb + r];
            pk[r] = (short)f2bf(v > 0.f ? v : 0.f);
        }
        *(s16x4*)(H2 + l15 * 136 + chb) = pk;
    }

    // ================= GEMM3: [256 x 128] * [128 x 16], two halves to cap VGPRs =================
    for (int half = 0; half < 2; ++half) {
        f32x4 acc3[8];
        #pragma unroll
        for (int t = 0; t < 8; ++t) acc3[t] = (f32x4){0.f, 0.f, 0.f, 0.f};
        #pragma unroll
        for (int kb = 0; kb < 4; ++kb) {
            const int k = kb * 32 + grp * 8;
            bf16x8 bfrag = *(const bf16x8*)(H2 + l15 * 136 + k);
            #pragma unroll
            for (int t = 0; t < 8; ++t) {
                bf16x8 afrag = *(const bf16x8*)(w3b + ((half * 8 + t) * 16 + l15) * 128 + k);
                acc3[t] = __builtin_amdgcn_mfma_f32_16x16x32_bf16(afrag, bfrag, acc3[t], 0, 0, 0);
            }
        }
        #pragma unroll
        for (int t = 0; t < 8; ++t) {
            #pragma unroll
            for (int r = 0; r < 4; ++r) {
                const int ch = (half * 8 + t) * 16 + grp * 4 + r;
                out[(((size_t)(b * 256 + ch)) << 14) + n] = acc3[t][r] + b3[ch];
            }
        }
    }
}

extern "C" void kernel_launch(void* const* d_in, const int* in_sizes, int n_in,
                              void* d_out, int out_size, void* d_ws, size_t ws_size,
                              hipStream_t stream)
{
    const float* feature = (const float*)d_in[0];
    const int*   idx     = (const int*)d_in[1];
    const float* dis     = (const float*)d_in[2];
    const float* W1      = (const float*)d_in[3];
    const float* b1      = (const float*)d_in[4];
    const float* W2      = (const float*)d_in[5];
    const float* b2      = (const float*)d_in[6];
    const float* W3      = (const float*)d_in[7];
    const float* b3      = (const float*)d_in[8];
    float* out = (float*)d_out;

    char* ws = (char*)d_ws;
    unsigned short* featT = (unsigned short*)ws;
    unsigned short* disB  = (unsigned short*)(ws + OFF_DISB);
    unsigned short* w1b   = (unsigned short*)(ws + OFF_W1B);
    unsigned short* w2b   = (unsigned short*)(ws + OFF_W2B);
    unsigned short* w3b   = (unsigned short*)(ws + OFF_W3B);

    hipLaunchKernelGGL(prep_misc, dim3(976), dim3(256), 0, stream,
                       dis, W1, W2, W3, disB, w1b, w2b, w3b);
    hipLaunchKernelGGL(prep_featT, dim3(512), dim3(256), 0, stream, feature, featT);
    hipLaunchKernelGGL(pointconv_main, dim3(2048), dim3(256), 0, stream,
                       featT, disB, idx, w1b, w2b, w3b, b1, b2, b3, out);
}

// Round 3
// 126.125 us; speedup vs baseline: 1.7053x; 1.7053x over previous
//
#include <hip/hip_runtime.h>
#include <hip/hip_bf16.h>
#include <stdint.h>

// Problem constants
#define BB 8
#define CC 64
#define NN 16384
#define KNB 8            // neighbors
// Padded GEMM1 K: cols 0..7 = dis[k], cols 8+kk*64+c = feature[c][idx[kk]], 520..543 = 0
#define K1P 544

typedef __attribute__((ext_vector_type(8))) short   s16x8;
typedef __attribute__((ext_vector_type(4))) short   s16x4;
typedef __attribute__((ext_vector_type(8))) __bf16  bf16x8;
typedef __attribute__((ext_vector_type(4))) float   f32x4;

__device__ __forceinline__ unsigned short f2bf(float f) {
    unsigned u = __builtin_bit_cast(unsigned, f);
    u = (u + 0x7FFFu + ((u >> 16) & 1u)) >> 16;   // RNE, inputs finite
    return (unsigned short)u;
}

// ---- workspace layout (bytes) ----
// featT [B][N][64] bf16 : 16,777,216   @ 0
// disB  [B][N][8]  bf16 :  2,097,152   @ 16,777,216
// W1p   frag-major      :    139,264   @ 18,874,368   (17 kb * 8 t * 64 lane * 8 elems)
// W2p   frag-major      :     32,768   @ 19,013,632   ( 4 kb * 8 t * 64 * 8)
// W3p   frag-major      :     65,536   @ 19,046,400   ( 2 half * 4 kb * 8 t * 64 * 8)
#define OFF_DISB  16777216u
#define OFF_W1B   18874368u
#define OFF_W2B   19013632u
#define OFF_W3B   19046400u

// ---------------- prep: dis->bf16, weights->bf16 fragment-major ----------------
// Weight fragments are stored so the main kernel's A-fragment load is
//   base + (fragId*64 + lane)*8 elems  -> lane-consecutive 16B, fully coalesced.
// Thread budget: 131072 (dis) + 8704 (W1p frags) + 2048 (W2p) + 4096 (W3p)
//              = 145,920 = 570 blocks * 256
__global__ __launch_bounds__(256) void prep_misc(
    const float* __restrict__ dis, const float* __restrict__ W1,
    const float* __restrict__ W2, const float* __restrict__ W3,
    unsigned short* __restrict__ disB, unsigned short* __restrict__ w1p,
    unsigned short* __restrict__ w2p, unsigned short* __restrict__ w3p)
{
    int tid = blockIdx.x * 256 + threadIdx.x;
    if (tid < 131072) {                        // one POINT per thread: 8 dis values
        const float* dp = dis + (size_t)tid * 8;
        s16x8 pk;
        #pragma unroll
        for (int j = 0; j < 8; ++j) pk[j] = (short)f2bf(dp[j]);
        *(s16x8*)(disB + (size_t)tid * 8) = pk;
        return;
    }
    int t2 = tid - 131072;
    if (t2 < 8704) {                           // W1p: kb 0..16, t 0..7, lane 0..63
        int kb   = t2 >> 9;
        int rem  = t2 & 511;
        int t    = rem >> 6;
        int lane = rem & 63;
        int row  = t * 16 + (lane & 15);
        int kbase = kb * 32 + (lane >> 4) * 8;
        s16x8 pk;
        #pragma unroll
        for (int j = 0; j < 8; ++j) {
            int kp = kbase + j;
            float val = 0.f;
            if (kp < 8)       val = W1[row * 520 + kp * 65];          // dis weight, neighbor kp
            else if (kp < 520) {
                int kk = (kp - 8) >> 6, c = (kp - 8) & 63;
                val = W1[row * 520 + kk * 65 + 1 + c];                // feature weight
            }
            pk[j] = (short)f2bf(val);
        }
        *(s16x8*)(w1p + (size_t)t2 * 8) = pk;
    } else if (t2 < 8704 + 2048) {             // W2p: kb 0..3, t 0..7, lane
        int f    = t2 - 8704;
        int kb   = f >> 9;
        int rem  = f & 511;
        int t    = rem >> 6;
        int lane = rem & 63;
        int row  = t * 16 + (lane & 15);
        int k    = kb * 32 + (lane >> 4) * 8;
        s16x8 pk;
        #pragma unroll
        for (int j = 0; j < 8; ++j) pk[j] = (short)f2bf(W2[row * 128 + k + j]);
        *(s16x8*)(w2p + (size_t)f * 8) = pk;
    } else if (t2 < 8704 + 2048 + 4096) {      // W3p: half 0..1, kb 0..3, t 0..7, lane
        int f    = t2 - 10752;
        int hk   = f >> 9;                     // half*4 + kb
        int half = hk >> 2, kb = hk & 3;
        int rem  = f & 511;
        int t    = rem >> 6;
        int lane = rem & 63;
        int row  = (half * 8 + t) * 16 + (lane & 15);
        int k    = kb * 32 + (lane >> 4) * 8;
        s16x8 pk;
        #pragma unroll
        for (int j = 0; j < 8; ++j) pk[j] = (short)f2bf(W3[row * 128 + k + j]);
        *(s16x8*)(w3p + (size_t)f * 8) = pk;
    }
}

// ---------------- prep: feature [B][C][N] fp32 -> featT [B][N][C] bf16 ----------------
__global__ __launch_bounds__(256) void prep_featT(
    const float* __restrict__ feat, unsigned short* __restrict__ featT)
{
    int gt = blockIdx.x * 256 + threadIdx.x;   // global point 0..131071
    int b = gt >> 14, n = gt & 16383;
    const float* fp = feat + ((size_t)b << 20) + n;     // b*64*16384
    unsigned short v[64];
    #pragma unroll
    for (int c = 0; c < 64; ++c) v[c] = f2bf(fp[(size_t)c << 14]);  // coalesced across lanes
    unsigned short* dst = featT + (size_t)gt * 64;
    #pragma unroll
    for (int j = 0; j < 8; ++j) {
        s16x8 pk;
        #pragma unroll
        for (int i = 0; i < 8; ++i) pk[i] = (short)v[j * 8 + i];
        *(s16x8*)(dst + j * 8) = pk;
    }
}

// ---------------- main fused kernel ----------------
// Block = 256 thr = 4 waves; each wave owns 16 consecutive points end-to-end (no barriers).
// Orientation: D[ch][pt] = W * X^T  so stores are n-contiguous.
// MFMA 16x16x32 bf16: A[i=lane&15][k=(lane>>4)*8+j], B[k][lane&15], D col=lane&15, row=(lane>>4)*4+r.
// All weight A-fragments are pre-swizzled fragment-major -> coalesced 16B/lane loads.
// XCD swizzle: 2048 blocks % 8 == 0; each XCD's 256 blocks cover exactly one batch b
// -> featT gather slice (2 MB) is per-XCD-L2-resident.
__global__ __launch_bounds__(256, 4) void pointconv_main(
    const unsigned short* __restrict__ featT,
    const unsigned short* __restrict__ disB,
    const int* __restrict__ idx,
    const unsigned short* __restrict__ w1p,
    const unsigned short* __restrict__ w2p,
    const unsigned short* __restrict__ w3p,
    const float* __restrict__ b1, const float* __restrict__ b2,
    const float* __restrict__ b3, float* __restrict__ out)
{
    __shared__ __align__(16) unsigned short hl[4 * 2 * 16 * 136];  // per-wave H1/H2 strips, stride 136
    const int bid  = blockIdx.x;
    const int wg   = (bid & 7) * 256 + (bid >> 3);     // XCD-aware bijective swizzle
    const int tid  = threadIdx.x;
    const int wv   = tid >> 6;
    const int lane = tid & 63;
    const int grp  = lane >> 4;
    const int l15  = lane & 15;
    const int p    = wg * 64 + wv * 16 + l15;          // this lane's point (B-frag / store role)
    const int b    = p >> 14;
    const int n    = p & 16383;

    unsigned short* H1 = hl + wv * (2 * 16 * 136);
    unsigned short* H2 = H1 + 16 * 136;

    // ================= GEMM1: [128 x 544] * [544 x 16] =================
    f32x4 acc[8];
    #pragma unroll
    for (int t = 0; t < 8; ++t) acc[t] = (f32x4){0.f, 0.f, 0.f, 0.f};

    const size_t featRow = ((size_t)b << 14);
    const int idxBase = p * 8;

    #pragma unroll
    for (int kb = 0; kb < 17; ++kb) {
        const int k = kb * 32 + grp * 8;
        bf16x8 bfrag;
        if (kb == 0 && grp == 0) {
            bfrag = *(const bf16x8*)(disB + (size_t)p * 8);        // 8 dis values
        } else if (k < 520) {
            const int kk = (k - 8) >> 6;
            const int c0 = (k - 8) & 63;
            const int iv = idx[idxBase + kk];                      // neighbor index
            bfrag = *(const bf16x8*)(featT + ((featRow + (size_t)iv) << 6) + c0); // 16B gather
        } else {
            bfrag = __builtin_bit_cast(bf16x8, (s16x8){0,0,0,0,0,0,0,0});
        }
        #pragma unroll
        for (int t = 0; t < 8; ++t) {
            bf16x8 afrag = *(const bf16x8*)(w1p + (size_t)((kb * 8 + t) * 64 + lane) * 8);
            acc[t] = __builtin_amdgcn_mfma_f32_16x16x32_bf16(afrag, bfrag, acc[t], 0, 0, 0);
        }
    }
    // epilogue 1: bias + relu -> H1[pt][ch] bf16
    #pragma unroll
    for (int t = 0; t < 8; ++t) {
        const int chb = t * 16 + grp * 4;
        s16x4 pk;
        #pragma unroll
        for (int r = 0; r < 4; ++r) {
            float v = acc[t][r] + b1[chb + r];
            pk[r] = (short)f2bf(v > 0.f ? v : 0.f);
        }
        *(s16x4*)(H1 + l15 * 136 + chb) = pk;
    }

    // ================= GEMM2: [128 x 128] * [128 x 16] =================
    f32x4 acc2[8];
    #pragma unroll
    for (int t = 0; t < 8; ++t) acc2[t] = (f32x4){0.f, 0.f, 0.f, 0.f};
    #pragma unroll
    for (int kb = 0; kb < 4; ++kb) {
        const int k = kb * 32 + grp * 8;
        bf16x8 bfrag = *(const bf16x8*)(H1 + l15 * 136 + k);
        #pragma unroll
        for (int t = 0; t < 8; ++t) {
            bf16x8 afrag = *(const bf16x8*)(w2p + (size_t)((kb * 8 + t) * 64 + lane) * 8);
            acc2[t] = __builtin_amdgcn_mfma_f32_16x16x32_bf16(afrag, bfrag, acc2[t], 0, 0, 0);
        }
    }
    #pragma unroll
    for (int t = 0; t < 8; ++t) {
        const int chb = t * 16 + grp * 4;
        s16x4 pk;
        #pragma unroll
        for (int r = 0; r < 4; ++r) {
            float v = acc2[t][r] + b2[chb + r];
            pk[r] = (short)f2bf(v > 0.f ? v : 0.f);
        }
        *(s16x4*)(H2 + l15 * 136 + chb) = pk;
    }

    // ================= GEMM3: [256 x 128] * [128 x 16], two halves to cap VGPRs =================
    for (int half = 0; half < 2; ++half) {
        f32x4 acc3[8];
        #pragma unroll
        for (int t = 0; t < 8; ++t) acc3[t] = (f32x4){0.f, 0.f, 0.f, 0.f};
        #pragma unroll
        for (int kb = 0; kb < 4; ++kb) {
            const int k = kb * 32 + grp * 8;
            bf16x8 bfrag = *(const bf16x8*)(H2 + l15 * 136 + k);
            #pragma unroll
            for (int t = 0; t < 8; ++t) {
                bf16x8 afrag = *(const bf16x8*)(w3p + (size_t)(((half * 4 + kb) * 8 + t) * 64 + lane) * 8);
                acc3[t] = __builtin_amdgcn_mfma_f32_16x16x32_bf16(afrag, bfrag, acc3[t], 0, 0, 0);
            }
        }
        #pragma unroll
        for (int t = 0; t < 8; ++t) {
            #pragma unroll
            for (int r = 0; r < 4; ++r) {
                const int ch = (half * 8 + t) * 16 + grp * 4 + r;
                out[(((size_t)(b * 256 + ch)) << 14) + n] = acc3[t][r] + b3[ch];
            }
        }
    }
}

extern "C" void kernel_launch(void* const* d_in, const int* in_sizes, int n_in,
                              void* d_out, int out_size, void* d_ws, size_t ws_size,
                              hipStream_t stream)
{
    const float* feature = (const float*)d_in[0];
    const int*   idx     = (const int*)d_in[1];
    const float* dis     = (const float*)d_in[2];
    const float* W1      = (const float*)d_in[3];
    const float* b1      = (const float*)d_in[4];
    const float* W2      = (const float*)d_in[5];
    const float* b2      = (const float*)d_in[6];
    const float* W3      = (const float*)d_in[7];
    const float* b3      = (const float*)d_in[8];
    float* out = (float*)d_out;

    char* ws = (char*)d_ws;
    unsigned short* featT = (unsigned short*)ws;
    unsigned short* disB  = (unsigned short*)(ws + OFF_DISB);
    unsigned short* w1p   = (unsigned short*)(ws + OFF_W1B);
    unsigned short* w2p   = (unsigned short*)(ws + OFF_W2B);
    unsigned short* w3p   = (unsigned short*)(ws + OFF_W3B);

    hipLaunchKernelGGL(prep_misc, dim3(570), dim3(256), 0, stream,
                       dis, W1, W2, W3, disB, w1p, w2p, w3p);
    hipLaunchKernelGGL(prep_featT, dim3(512), dim3(256), 0, stream, feature, featT);
    hipLaunchKernelGGL(pointconv_main, dim3(2048), dim3(256), 0, stream,
                       featT, disB, idx, w1p, w2p, w3p, b1, b2, b3, out);
}

// Round 4
// 107.658 us; speedup vs baseline: 1.9978x; 1.1715x over previous
//
#include <hip/hip_runtime.h>
#include <hip/hip_bf16.h>
#include <stdint.h>

// Problem constants
#define BB 8
#define CC 64
#define NN 16384
#define KNB 8            // neighbors
// Padded GEMM1 K (REPERMUTED): cols kk*64+c = feature[c][idx[kk]] for kk=0..7,
// cols 512..519 = dis[0..7], cols 520..543 = 0.  (17 kb-steps of 32)
#define K1P 544

typedef __attribute__((ext_vector_type(8))) short   s16x8;
typedef __attribute__((ext_vector_type(4))) short   s16x4;
typedef __attribute__((ext_vector_type(8))) __bf16  bf16x8;
typedef __attribute__((ext_vector_type(4))) float   f32x4;

__device__ __forceinline__ unsigned short f2bf(float f) {
    unsigned u = __builtin_bit_cast(unsigned, f);
    u = (u + 0x7FFFu + ((u >> 16) & 1u)) >> 16;   // RNE, inputs finite
    return (unsigned short)u;
}

__device__ __forceinline__ int getq(const int4& q, int j) {
    return j == 0 ? q.x : j == 1 ? q.y : j == 2 ? q.z : q.w;   // j constant-folds after unroll
}

// ---- workspace layout (bytes) ----
// featT [B][N][64] bf16 : 16,777,216   @ 0
// disB  [B][N][8]  bf16 :  2,097,152   @ 16,777,216
// W1p   frag-major      :    139,264   @ 18,874,368   (17 kb * 8 t * 64 lane * 8 elems)
// W2p   frag-major      :     32,768   @ 19,013,632   ( 4 kb * 8 t * 64 * 8)
// W3p   frag-major      :     65,536   @ 19,046,400   ( 2 half * 4 kb * 8 t * 64 * 8)
#define OFF_DISB  16777216u
#define OFF_W1B   18874368u
#define OFF_W2B   19013632u
#define OFF_W3B   19046400u

// ---------------- prep: dis->bf16, weights->bf16 fragment-major ----------------
// Thread budget: 131072 (dis) + 8704 (W1p frags) + 2048 (W2p) + 4096 (W3p)
//              = 145,920 = 570 blocks * 256
__global__ __launch_bounds__(256) void prep_misc(
    const float* __restrict__ dis, const float* __restrict__ W1,
    const float* __restrict__ W2, const float* __restrict__ W3,
    unsigned short* __restrict__ disB, unsigned short* __restrict__ w1p,
    unsigned short* __restrict__ w2p, unsigned short* __restrict__ w3p)
{
    int tid = blockIdx.x * 256 + threadIdx.x;
    if (tid < 131072) {                        // one POINT per thread: 8 dis values
        const float* dp = dis + (size_t)tid * 8;
        s16x8 pk;
        #pragma unroll
        for (int j = 0; j < 8; ++j) pk[j] = (short)f2bf(dp[j]);
        *(s16x8*)(disB + (size_t)tid * 8) = pk;
        return;
    }
    int t2 = tid - 131072;
    if (t2 < 8704) {                           // W1p: kb 0..16, t 0..7, lane 0..63
        int kb   = t2 >> 9;
        int rem  = t2 & 511;
        int t    = rem >> 6;
        int lane = rem & 63;
        int row  = t * 16 + (lane & 15);
        int kbase = kb * 32 + (lane >> 4) * 8;
        s16x8 pk;
        #pragma unroll
        for (int j = 0; j < 8; ++j) {
            int kp = kbase + j;
            float val = 0.f;
            if (kp < 512) {                                          // feature weights
                int kk = kp >> 6, c = kp & 63;
                val = W1[row * 520 + kk * 65 + 1 + c];
            } else if (kp < 520) {                                   // dis weight of neighbor kp-512
                val = W1[row * 520 + (kp - 512) * 65];
            }
            pk[j] = (short)f2bf(val);
        }
        *(s16x8*)(w1p + (size_t)t2 * 8) = pk;
    } else if (t2 < 8704 + 2048) {             // W2p: kb 0..3, t 0..7, lane
        int f    = t2 - 8704;
        int kb   = f >> 9;
        int rem  = f & 511;
        int t    = rem >> 6;
        int lane = rem & 63;
        int row  = t * 16 + (lane & 15);
        int k    = kb * 32 + (lane >> 4) * 8;
        s16x8 pk;
        #pragma unroll
        for (int j = 0; j < 8; ++j) pk[j] = (short)f2bf(W2[row * 128 + k + j]);
        *(s16x8*)(w2p + (size_t)f * 8) = pk;
    } else if (t2 < 8704 + 2048 + 4096) {      // W3p: half 0..1, kb 0..3, t 0..7, lane
        int f    = t2 - 10752;
        int hk   = f >> 9;                     // half*4 + kb
        int half = hk >> 2, kb = hk & 3;
        int rem  = f & 511;
        int t    = rem >> 6;
        int lane = rem & 63;
        int row  = (half * 8 + t) * 16 + (lane & 15);
        int k    = kb * 32 + (lane >> 4) * 8;
        s16x8 pk;
        #pragma unroll
        for (int j = 0; j < 8; ++j) pk[j] = (short)f2bf(W3[row * 128 + k + j]);
        *(s16x8*)(w3p + (size_t)f * 8) = pk;
    }
}

// ---------------- prep: feature [B][C][N] fp32 -> featT [B][N][C] bf16 ----------------
__global__ __launch_bounds__(256) void prep_featT(
    const float* __restrict__ feat, unsigned short* __restrict__ featT)
{
    int gt = blockIdx.x * 256 + threadIdx.x;   // global point 0..131071
    int b = gt >> 14, n = gt & 16383;
    const float* fp = feat + ((size_t)b << 20) + n;     // b*64*16384
    unsigned short v[64];
    #pragma unroll
    for (int c = 0; c < 64; ++c) v[c] = f2bf(fp[(size_t)c << 14]);  // coalesced across lanes
    unsigned short* dst = featT + (size_t)gt * 64;
    #pragma unroll
    for (int j = 0; j < 8; ++j) {
        s16x8 pk;
        #pragma unroll
        for (int i = 0; i < 8; ++i) pk[i] = (short)v[j * 8 + i];
        *(s16x8*)(dst + j * 8) = pk;
    }
}

// ---------------- main fused kernel ----------------
// 1 wave (64 thr) per block; each wave owns 64 consecutive points (4 pt-tiles of 16).
// ptile-inner MFMA loops: every weight fragment load feeds 4 MFMAs (4x L1-pipe amortization).
// Orientation: D[ch][pt] = W * X^T.  MFMA 16x16x32 bf16:
//   A[i=lane&15][k=(lane>>4)*8+j], B[k][lane&15], D col=lane&15, row=(lane>>4)*4+r.
// H1/H2 round-trip through a per-wave LDS strip (stride 136 shorts); zero barriers.
// XCD swizzle: 2048 blocks, each XCD's 256 blocks cover exactly one batch b.
__global__ __launch_bounds__(64, 2) void pointconv_main(
    const unsigned short* __restrict__ featT,
    const unsigned short* __restrict__ disB,
    const int* __restrict__ idx,
    const unsigned short* __restrict__ w1p,
    const unsigned short* __restrict__ w2p,
    const unsigned short* __restrict__ w3p,
    const float* __restrict__ b1, const float* __restrict__ b2,
    const float* __restrict__ b3, float* __restrict__ out)
{
    __shared__ __align__(16) unsigned short strip[64 * 136];   // 17,408 B per wave
    const int bid  = blockIdx.x;
    const int wg   = (bid & 7) * 256 + (bid >> 3);     // XCD-aware bijective swizzle
    const int lane = threadIdx.x;                      // 0..63
    const int grp  = lane >> 4;
    const int l15  = lane & 15;
    const int p0   = wg * 64;                          // block's first point
    const int b    = p0 >> 14;                         // uniform per block
    const int n0   = p0 & 16383;

    // ---- preload this lane's idx rows: pt(ptile) = p0 + ptile*16 + l15 ----
    int4 idxq[4][2];
    #pragma unroll
    for (int pt = 0; pt < 4; ++pt) {
        const int* ip = idx + (size_t)(p0 + pt * 16 + l15) * 8;
        idxq[pt][0] = *(const int4*)ip;
        idxq[pt][1] = *(const int4*)(ip + 4);
    }

    const unsigned short* featB = featT + ((size_t)b << 20);   // b * 16384 * 64

    // ================= GEMM1: [128 x 544] * [544 x 64] =================
    f32x4 acc[8][4];
    #pragma unroll
    for (int t = 0; t < 8; ++t)
        #pragma unroll
        for (int pt = 0; pt < 4; ++pt) acc[t][pt] = (f32x4){0.f, 0.f, 0.f, 0.f};

    #pragma unroll
    for (int kb = 0; kb < 16; ++kb) {
        const int kk = kb >> 1;                         // static per unrolled step
        const int c0 = (kb & 1) * 32 + grp * 8;         // channel offset (runtime, addr math only)
        bf16x8 bfr[4];
        #pragma unroll
        for (int pt = 0; pt < 4; ++pt) {
            const int iv = getq(idxq[pt][kk >> 2], kk & 3);
            bfr[pt] = *(const bf16x8*)(featB + (((size_t)iv) << 6) + c0);   // 16B gather
        }
        #pragma unroll
        for (int t = 0; t < 8; ++t) {
            bf16x8 afrag = *(const bf16x8*)(w1p + (size_t)((kb * 8 + t) * 64 + lane) * 8);
            #pragma unroll
            for (int pt = 0; pt < 4; ++pt)
                acc[t][pt] = __builtin_amdgcn_mfma_f32_16x16x32_bf16(afrag, bfr[pt], acc[t][pt], 0, 0, 0);
        }
    }
    {   // kb = 16: cols 512..519 = dis (grp 0 only), 520..543 = zero pad
        bf16x8 bfr[4];
        #pragma unroll
        for (int pt = 0; pt < 4; ++pt) bfr[pt] = __builtin_bit_cast(bf16x8, (s16x8){0,0,0,0,0,0,0,0});
        if (grp == 0) {
            #pragma unroll
            for (int pt = 0; pt < 4; ++pt)
                bfr[pt] = *(const bf16x8*)(disB + (size_t)(p0 + pt * 16 + l15) * 8);
        }
        #pragma unroll
        for (int t = 0; t < 8; ++t) {
            bf16x8 afrag = *(const bf16x8*)(w1p + (size_t)((16 * 8 + t) * 64 + lane) * 8);
            #pragma unroll
            for (int pt = 0; pt < 4; ++pt)
                acc[t][pt] = __builtin_amdgcn_mfma_f32_16x16x32_bf16(afrag, bfr[pt], acc[t][pt], 0, 0, 0);
        }
    }
    // epilogue 1: bias + relu -> strip[pt][ch] bf16
    #pragma unroll
    for (int t = 0; t < 8; ++t) {
        const int chb = t * 16 + grp * 4;
        const float4 bv = *(const float4*)(b1 + chb);
        #pragma unroll
        for (int pt = 0; pt < 4; ++pt) {
            s16x4 pk;
            float v0 = acc[t][pt][0] + bv.x; pk[0] = (short)f2bf(v0 > 0.f ? v0 : 0.f);
            float v1 = acc[t][pt][1] + bv.y; pk[1] = (short)f2bf(v1 > 0.f ? v1 : 0.f);
            float v2 = acc[t][pt][2] + bv.z; pk[2] = (short)f2bf(v2 > 0.f ? v2 : 0.f);
            float v3 = acc[t][pt][3] + bv.w; pk[3] = (short)f2bf(v3 > 0.f ? v3 : 0.f);
            *(s16x4*)(strip + (pt * 16 + l15) * 136 + chb) = pk;
        }
    }

    // ================= GEMM2: [128 x 128] * [128 x 64] =================
    f32x4 acc2[8][4];
    #pragma unroll
    for (int t = 0; t < 8; ++t)
        #pragma unroll
        for (int pt = 0; pt < 4; ++pt) acc2[t][pt] = (f32x4){0.f, 0.f, 0.f, 0.f};
    #pragma unroll
    for (int kb = 0; kb < 4; ++kb) {
        bf16x8 bfr[4];
        #pragma unroll
        for (int pt = 0; pt < 4; ++pt)
            bfr[pt] = *(const bf16x8*)(strip + (pt * 16 + l15) * 136 + kb * 32 + grp * 8);
        #pragma unroll
        for (int t = 0; t < 8; ++t) {
            bf16x8 afrag = *(const bf16x8*)(w2p + (size_t)((kb * 8 + t) * 64 + lane) * 8);
            #pragma unroll
            for (int pt = 0; pt < 4; ++pt)
                acc2[t][pt] = __builtin_amdgcn_mfma_f32_16x16x32_bf16(afrag, bfr[pt], acc2[t][pt], 0, 0, 0);
        }
    }
    // epilogue 2: bias + relu -> strip (H1 fully consumed; same-wave ordering, no barrier)
    #pragma unroll
    for (int t = 0; t < 8; ++t) {
        const int chb = t * 16 + grp * 4;
        const float4 bv = *(const float4*)(b2 + chb);
        #pragma unroll
        for (int pt = 0; pt < 4; ++pt) {
            s16x4 pk;
            float v0 = acc2[t][pt][0] + bv.x; pk[0] = (short)f2bf(v0 > 0.f ? v0 : 0.f);
            float v1 = acc2[t][pt][1] + bv.y; pk[1] = (short)f2bf(v1 > 0.f ? v1 : 0.f);
            float v2 = acc2[t][pt][2] + bv.z; pk[2] = (short)f2bf(v2 > 0.f ? v2 : 0.f);
            float v3 = acc2[t][pt][3] + bv.w; pk[3] = (short)f2bf(v3 > 0.f ? v3 : 0.f);
            *(s16x4*)(strip + (pt * 16 + l15) * 136 + chb) = pk;
        }
    }

    // ================= GEMM3: [256 x 128] * [128 x 64], two halves =================
    #pragma unroll
    for (int half = 0; half < 2; ++half) {
        f32x4 acc3[8][4];
        #pragma unroll
        for (int t = 0; t < 8; ++t)
            #pragma unroll
            for (int pt = 0; pt < 4; ++pt) acc3[t][pt] = (f32x4){0.f, 0.f, 0.f, 0.f};
        #pragma unroll
        for (int kb = 0; kb < 4; ++kb) {
            bf16x8 bfr[4];
            #pragma unroll
            for (int pt = 0; pt < 4; ++pt)
                bfr[pt] = *(const bf16x8*)(strip + (pt * 16 + l15) * 136 + kb * 32 + grp * 8);
            #pragma unroll
            for (int t = 0; t < 8; ++t) {
                bf16x8 afrag = *(const bf16x8*)(w3p + (size_t)(((half * 4 + kb) * 8 + t) * 64 + lane) * 8);
                #pragma unroll
                for (int pt = 0; pt < 4; ++pt)
                    acc3[t][pt] = __builtin_amdgcn_mfma_f32_16x16x32_bf16(afrag, bfr[pt], acc3[t][pt], 0, 0, 0);
            }
        }
        #pragma unroll
        for (int t = 0; t < 8; ++t) {
            const int chb = half * 128 + t * 16 + grp * 4;
            const float4 bv = *(const float4*)(b3 + chb);
            #pragma unroll
            for (int pt = 0; pt < 4; ++pt) {
                const int n = n0 + pt * 16 + l15;
                float* op = out + (((size_t)(b * 256 + chb)) << 14) + n;
                __builtin_nontemporal_store(acc3[t][pt][0] + bv.x, op);
                __builtin_nontemporal_store(acc3[t][pt][1] + bv.y, op + (1u << 14));
                __builtin_nontemporal_store(acc3[t][pt][2] + bv.z, op + (2u << 14));
                __builtin_nontemporal_store(acc3[t][pt][3] + bv.w, op + (3u << 14));
            }
        }
    }
}

extern "C" void kernel_launch(void* const* d_in, const int* in_sizes, int n_in,
                              void* d_out, int out_size, void* d_ws, size_t ws_size,
                              hipStream_t stream)
{
    const float* feature = (const float*)d_in[0];
    const int*   idx     = (const int*)d_in[1];
    const float* dis     = (const float*)d_in[2];
    const float* W1      = (const float*)d_in[3];
    const float* b1      = (const float*)d_in[4];
    const float* W2      = (const float*)d_in[5];
    const float* b2      = (const float*)d_in[6];
    const float* W3      = (const float*)d_in[7];
    const float* b3      = (const float*)d_in[8];
    float* out = (float*)d_out;

    char* ws = (char*)d_ws;
    unsigned short* featT = (unsigned short*)ws;
    unsigned short* disB  = (unsigned short*)(ws + OFF_DISB);
    unsigned short* w1p   = (unsigned short*)(ws + OFF_W1B);
    unsigned short* w2p   = (unsigned short*)(ws + OFF_W2B);
    unsigned short* w3p   = (unsigned short*)(ws + OFF_W3B);

    hipLaunchKernelGGL(prep_misc, dim3(570), dim3(256), 0, stream,
                       dis, W1, W2, W3, disB, w1p, w2p, w3p);
    hipLaunchKernelGGL(prep_featT, dim3(512), dim3(256), 0, stream, feature, featT);
    hipLaunchKernelGGL(pointconv_main, dim3(2048), dim3(64), 0, stream,
                       featT, disB, idx, w1p, w2p, w3p, b1, b2, b3, out);
}

// Round 6
// 77.829 us; speedup vs baseline: 2.7635x; 1.3833x over previous
//
#include <hip/hip_runtime.h>
#include <hip/hip_bf16.h>
#include <stdint.h>

// Problem constants
#define BB 8
#define CC 64
#define NN 16384
#define KNB 8            // neighbors
// Padded GEMM1 K (REPERMUTED): cols kk*64+c = feature[c][idx[kk]] for kk=0..7,
// cols 512..519 = dis[0..7], cols 520..543 = 0.  (17 kb-steps of 32)

typedef __attribute__((ext_vector_type(8))) short   s16x8;
typedef __attribute__((ext_vector_type(4))) short   s16x4;
typedef __attribute__((ext_vector_type(8))) __bf16  bf16x8;
typedef __attribute__((ext_vector_type(4))) float   f32x4;

__device__ __forceinline__ unsigned short f2bf(float f) {
    unsigned u = __builtin_bit_cast(unsigned, f);
    u = (u + 0x7FFFu + ((u >> 16) & 1u)) >> 16;   // RNE, inputs finite
    return (unsigned short)u;
}

__device__ __forceinline__ int getq(const int4& q, int j) {
    return j == 0 ? q.x : j == 1 ? q.y : j == 2 ? q.z : q.w;   // j constant-folds after unroll
}

// ---- workspace layout (bytes) ----
#define OFF_DISB  16777216u
#define OFF_W1B   18874368u
#define OFF_W2B   19013632u
#define OFF_W3B   19046400u

// ---------------- prep: dis->bf16, weights->bf16 fragment-major ----------------
__global__ __launch_bounds__(256) void prep_misc(
    const float* __restrict__ dis, const float* __restrict__ W1,
    const float* __restrict__ W2, const float* __restrict__ W3,
    unsigned short* __restrict__ disB, unsigned short* __restrict__ w1p,
    unsigned short* __restrict__ w2p, unsigned short* __restrict__ w3p)
{
    int tid = blockIdx.x * 256 + threadIdx.x;
    if (tid < 131072) {                        // one POINT per thread: 8 dis values
        const float* dp = dis + (size_t)tid * 8;
        s16x8 pk;
        #pragma unroll
        for (int j = 0; j < 8; ++j) pk[j] = (short)f2bf(dp[j]);
        *(s16x8*)(disB + (size_t)tid * 8) = pk;
        return;
    }
    int t2 = tid - 131072;
    if (t2 < 8704) {                           // W1p: kb 0..16, t 0..7, lane 0..63
        int kb   = t2 >> 9;
        int rem  = t2 & 511;
        int t    = rem >> 6;
        int lane = rem & 63;
        int row  = t * 16 + (lane & 15);
        int kbase = kb * 32 + (lane >> 4) * 8;
        s16x8 pk;
        #pragma unroll
        for (int j = 0; j < 8; ++j) {
            int kp = kbase + j;
            float val = 0.f;
            if (kp < 512) {                                          // feature weights
                int kk = kp >> 6, c = kp & 63;
                val = W1[row * 520 + kk * 65 + 1 + c];
            } else if (kp < 520) {                                   // dis weight of neighbor kp-512
                val = W1[row * 520 + (kp - 512) * 65];
            }
            pk[j] = (short)f2bf(val);
        }
        *(s16x8*)(w1p + (size_t)t2 * 8) = pk;
    } else if (t2 < 8704 + 2048) {             // W2p
        int f    = t2 - 8704;
        int kb   = f >> 9;
        int rem  = f & 511;
        int t    = rem >> 6;
        int lane = rem & 63;
        int row  = t * 16 + (lane & 15);
        int k    = kb * 32 + (lane >> 4) * 8;
        s16x8 pk;
        #pragma unroll
        for (int j = 0; j < 8; ++j) pk[j] = (short)f2bf(W2[row * 128 + k + j]);
        *(s16x8*)(w2p + (size_t)f * 8) = pk;
    } else if (t2 < 8704 + 2048 + 4096) {      // W3p
        int f    = t2 - 10752;
        int hk   = f >> 9;
        int half = hk >> 2, kb = hk & 3;
        int rem  = f & 511;
        int t    = rem >> 6;
        int lane = rem & 63;
        int row  = (half * 8 + t) * 16 + (lane & 15);
        int k    = kb * 32 + (lane >> 4) * 8;
        s16x8 pk;
        #pragma unroll
        for (int j = 0; j < 8; ++j) pk[j] = (short)f2bf(W3[row * 128 + k + j]);
        *(s16x8*)(w3p + (size_t)f * 8) = pk;
    }
}

// ---------------- prep: feature [B][C][N] fp32 -> featT [B][N][C] bf16 ----------------
__global__ __launch_bounds__(256) void prep_featT(
    const float* __restrict__ feat, unsigned short* __restrict__ featT)
{
    int gt = blockIdx.x * 256 + threadIdx.x;
    int b = gt >> 14, n = gt & 16383;
    const float* fp = feat + ((size_t)b << 20) + n;
    unsigned short v[64];
    #pragma unroll
    for (int c = 0; c < 64; ++c) v[c] = f2bf(fp[(size_t)c << 14]);
    unsigned short* dst = featT + (size_t)gt * 64;
    #pragma unroll
    for (int j = 0; j < 8; ++j) {
        s16x8 pk;
        #pragma unroll
        for (int i = 0; i < 8; ++i) pk[i] = (short)v[j * 8 + i];
        *(s16x8*)(dst + j * 8) = pk;
    }
}

// ---------------- main fused kernel helpers ----------------
__device__ __forceinline__ void wload4(const unsigned short* wp, int frag0, int lane,
                                       bf16x8& w0, bf16x8& w1, bf16x8& w2, bf16x8& w3)
{
    w0 = *(const bf16x8*)(wp + (size_t)((frag0 + 0) * 64 + lane) * 8);
    w1 = *(const bf16x8*)(wp + (size_t)((frag0 + 1) * 64 + lane) * 8);
    w2 = *(const bf16x8*)(wp + (size_t)((frag0 + 2) * 64 + lane) * 8);
    w3 = *(const bf16x8*)(wp + (size_t)((frag0 + 3) * 64 + lane) * 8);
}

template <int KB>
__device__ __forceinline__ void gather4(const unsigned short* featB, const int4 (&iq)[4][2],
                                        int grp8, bf16x8& G0, bf16x8& G1, bf16x8& G2, bf16x8& G3)
{
    constexpr int kk = KB >> 1;
    const int c0 = (KB & 1) * 32 + grp8;
    G0 = *(const bf16x8*)(featB + (((size_t)(unsigned)getq(iq[0][kk >> 2], kk & 3)) << 6) + c0);
    G1 = *(const bf16x8*)(featB + (((size_t)(unsigned)getq(iq[1][kk >> 2], kk & 3)) << 6) + c0);
    G2 = *(const bf16x8*)(featB + (((size_t)(unsigned)getq(iq[2][kk >> 2], kk & 3)) << 6) + c0);
    G3 = *(const bf16x8*)(featB + (((size_t)(unsigned)getq(iq[3][kk >> 2], kk & 3)) << 6) + c0);
}

// dis columns (kb=16 data): grp 0 lanes carry dis[0..7], other grps are zero pad
__device__ __forceinline__ void disload4(const unsigned short* disB, int p0, int l15, int grp,
                                         bf16x8& G0, bf16x8& G1, bf16x8& G2, bf16x8& G3)
{
    const s16x8 z = {0,0,0,0,0,0,0,0};
    if (grp == 0) {
        G0 = *(const bf16x8*)(disB + (size_t)(p0 +  0 + l15) * 8);
        G1 = *(const bf16x8*)(disB + (size_t)(p0 + 16 + l15) * 8);
        G2 = *(const bf16x8*)(disB + (size_t)(p0 + 32 + l15) * 8);
        G3 = *(const bf16x8*)(disB + (size_t)(p0 + 48 + l15) * 8);
    } else {
        G0 = __builtin_bit_cast(bf16x8, z); G1 = __builtin_bit_cast(bf16x8, z);
        G2 = __builtin_bit_cast(bf16x8, z); G3 = __builtin_bit_cast(bf16x8, z);
    }
}

__device__ __forceinline__ void dsread4(const unsigned short* strip, int kb, int l15, int grp8,
                                        bf16x8& G0, bf16x8& G1, bf16x8& G2, bf16x8& G3)
{
    G0 = *(const bf16x8*)(strip + (0 * 16 + l15) * 136 + kb * 32 + grp8);
    G1 = *(const bf16x8*)(strip + (1 * 16 + l15) * 136 + kb * 32 + grp8);
    G2 = *(const bf16x8*)(strip + (2 * 16 + l15) * 136 + kb * 32 + grp8);
    G3 = *(const bf16x8*)(strip + (3 * 16 + l15) * 136 + kb * 32 + grp8);
}

__device__ __forceinline__ void mfma_quad(f32x4 (&ac)[8][4], int t0,
    const bf16x8& wa, const bf16x8& wb, const bf16x8& wc, const bf16x8& wd,
    const bf16x8& B0, const bf16x8& B1, const bf16x8& B2, const bf16x8& B3)
{
    ac[t0+0][0] = __builtin_amdgcn_mfma_f32_16x16x32_bf16(wa, B0, ac[t0+0][0], 0, 0, 0);
    ac[t0+0][1] = __builtin_amdgcn_mfma_f32_16x16x32_bf16(wa, B1, ac[t0+0][1], 0, 0, 0);
    ac[t0+0][2] = __builtin_amdgcn_mfma_f32_16x16x32_bf16(wa, B2, ac[t0+0][2], 0, 0, 0);
    ac[t0+0][3] = __builtin_amdgcn_mfma_f32_16x16x32_bf16(wa, B3, ac[t0+0][3], 0, 0, 0);
    ac[t0+1][0] = __builtin_amdgcn_mfma_f32_16x16x32_bf16(wb, B0, ac[t0+1][0], 0, 0, 0);
    ac[t0+1][1] = __builtin_amdgcn_mfma_f32_16x16x32_bf16(wb, B1, ac[t0+1][1], 0, 0, 0);
    ac[t0+1][2] = __builtin_amdgcn_mfma_f32_16x16x32_bf16(wb, B2, ac[t0+1][2], 0, 0, 0);
    ac[t0+1][3] = __builtin_amdgcn_mfma_f32_16x16x32_bf16(wb, B3, ac[t0+1][3], 0, 0, 0);
    ac[t0+2][0] = __builtin_amdgcn_mfma_f32_16x16x32_bf16(wc, B0, ac[t0+2][0], 0, 0, 0);
    ac[t0+2][1] = __builtin_amdgcn_mfma_f32_16x16x32_bf16(wc, B1, ac[t0+2][1], 0, 0, 0);
    ac[t0+2][2] = __builtin_amdgcn_mfma_f32_16x16x32_bf16(wc, B2, ac[t0+2][2], 0, 0, 0);
    ac[t0+2][3] = __builtin_amdgcn_mfma_f32_16x16x32_bf16(wc, B3, ac[t0+2][3], 0, 0, 0);
    ac[t0+3][0] = __builtin_amdgcn_mfma_f32_16x16x32_bf16(wd, B0, ac[t0+3][0], 0, 0, 0);
    ac[t0+3][1] = __builtin_amdgcn_mfma_f32_16x16x32_bf16(wd, B1, ac[t0+3][1], 0, 0, 0);
    ac[t0+3][2] = __builtin_amdgcn_mfma_f32_16x16x32_bf16(wd, B2, ac[t0+3][2], 0, 0, 0);
    ac[t0+3][3] = __builtin_amdgcn_mfma_f32_16x16x32_bf16(wd, B3, ac[t0+3][3], 0, 0, 0);
}

// ---------------- main fused kernel ----------------
// 1 wave per block, 64 points per wave. Software-pipelined: gathers 2-deep reg dbuf,
// weights quad-dbuf threaded through all three GEMMs. Zero barriers.
__global__ __launch_bounds__(64, 2) void pointconv_main(
    const unsigned short* __restrict__ featT,
    const unsigned short* __restrict__ disB,
    const int* __restrict__ idx,
    const unsigned short* __restrict__ w1p,
    const unsigned short* __restrict__ w2p,
    const unsigned short* __restrict__ w3p,
    const float* __restrict__ b1, const float* __restrict__ b2,
    const float* __restrict__ b3, float* __restrict__ out)
{
    __shared__ __align__(16) unsigned short strip[64 * 136];   // 17,408 B
    const int bid  = blockIdx.x;
    const int wg   = (bid & 7) * 256 + (bid >> 3);     // XCD-aware bijective swizzle
    const int lane = threadIdx.x;                      // 0..63
    const int grp  = lane >> 4;
    const int grp8 = grp * 8;
    const int l15  = lane & 15;
    const int p0   = wg * 64;
    const int b    = p0 >> 14;
    const int n0   = p0 & 16383;

    // pipeline registers
    bf16x8 gA0, gA1, gA2, gA3, gB0, gB1, gB2, gB3;     // B-frag double buffer
    bf16x8 wA0, wA1, wA2, wA3, wB0, wB1, wB2, wB3;     // weight quad double buffer

    // ---- prolog: first weights, idx, first two gather sets ----
    wload4(w1p, 0, lane, wA0, wA1, wA2, wA3);          // Q(0,0)

    int4 idxq[4][2];
    #pragma unroll
    for (int pt = 0; pt < 4; ++pt) {
        const int* ip = idx + (size_t)(p0 + pt * 16 + l15) * 8;
        idxq[pt][0] = *(const int4*)ip;
        idxq[pt][1] = *(const int4*)(ip + 4);
    }
    const unsigned short* featB = featT + ((size_t)b << 20);

    gather4<0>(featB, idxq, grp8, gA0, gA1, gA2, gA3);
    gather4<1>(featB, idxq, grp8, gB0, gB1, gB2, gB3);

    // ================= GEMM1: [128 x 544] * [544 x 64] =================
    f32x4 acc[8][4];
    #pragma unroll
    for (int t = 0; t < 8; ++t)
        #pragma unroll
        for (int pt = 0; pt < 4; ++pt) acc[t][pt] = (f32x4){0.f, 0.f, 0.f, 0.f};

#define G1_BODY(KB, S0,S1,S2,S3, WNEXT, GNEXT)                              \
    wload4(w1p, (KB)*8 + 4, lane, wB0, wB1, wB2, wB3);                      \
    mfma_quad(acc, 0, wA0, wA1, wA2, wA3, S0, S1, S2, S3);                  \
    WNEXT;                                                                  \
    mfma_quad(acc, 4, wB0, wB1, wB2, wB3, S0, S1, S2, S3);                  \
    GNEXT;

    G1_BODY(0,  gA0,gA1,gA2,gA3, wload4(w1p,  8, lane, wA0,wA1,wA2,wA3), (gather4< 2>(featB, idxq, grp8, gA0,gA1,gA2,gA3)))
    G1_BODY(1,  gB0,gB1,gB2,gB3, wload4(w1p, 16, lane, wA0,wA1,wA2,wA3), (gather4< 3>(featB, idxq, grp8, gB0,gB1,gB2,gB3)))
    G1_BODY(2,  gA0,gA1,gA2,gA3, wload4(w1p, 24, lane, wA0,wA1,wA2,wA3), (gather4< 4>(featB, idxq, grp8, gA0,gA1,gA2,gA3)))
    G1_BODY(3,  gB0,gB1,gB2,gB3, wload4(w1p, 32, lane, wA0,wA1,wA2,wA3), (gather4< 5>(featB, idxq, grp8, gB0,gB1,gB2,gB3)))
    G1_BODY(4,  gA0,gA1,gA2,gA3, wload4(w1p, 40, lane, wA0,wA1,wA2,wA3), (gather4< 6>(featB, idxq, grp8, gA0,gA1,gA2,gA3)))
    G1_BODY(5,  gB0,gB1,gB2,gB3, wload4(w1p, 48, lane, wA0,wA1,wA2,wA3), (gather4< 7>(featB, idxq, grp8, gB0,gB1,gB2,gB3)))
    G1_BODY(6,  gA0,gA1,gA2,gA3, wload4(w1p, 56, lane, wA0,wA1,wA2,wA3), (gather4< 8>(featB, idxq, grp8, gA0,gA1,gA2,gA3)))
    G1_BODY(7,  gB0,gB1,gB2,gB3, wload4(w1p, 64, lane, wA0,wA1,wA2,wA3), (gather4< 9>(featB, idxq, grp8, gB0,gB1,gB2,gB3)))
    G1_BODY(8,  gA0,gA1,gA2,gA3, wload4(w1p, 72, lane, wA0,wA1,wA2,wA3), (gather4<10>(featB, idxq, grp8, gA0,gA1,gA2,gA3)))
    G1_BODY(9,  gB0,gB1,gB2,gB3, wload4(w1p, 80, lane, wA0,wA1,wA2,wA3), (gather4<11>(featB, idxq, grp8, gB0,gB1,gB2,gB3)))
    G1_BODY(10, gA0,gA1,gA2,gA3, wload4(w1p, 88, lane, wA0,wA1,wA2,wA3), (gather4<12>(featB, idxq, grp8, gA0,gA1,gA2,gA3)))
    G1_BODY(11, gB0,gB1,gB2,gB3, wload4(w1p, 96, lane, wA0,wA1,wA2,wA3), (gather4<13>(featB, idxq, grp8, gB0,gB1,gB2,gB3)))
    G1_BODY(12, gA0,gA1,gA2,gA3, wload4(w1p,104, lane, wA0,wA1,wA2,wA3), (gather4<14>(featB, idxq, grp8, gA0,gA1,gA2,gA3)))
    G1_BODY(13, gB0,gB1,gB2,gB3, wload4(w1p,112, lane, wA0,wA1,wA2,wA3), (gather4<15>(featB, idxq, grp8, gB0,gB1,gB2,gB3)))
    // kb=14: "next gather" slot loads the dis columns (kb=16 data) into the gA set
    G1_BODY(14, gA0,gA1,gA2,gA3, wload4(w1p,120, lane, wA0,wA1,wA2,wA3), disload4(disB, p0, l15, grp, gA0,gA1,gA2,gA3))
    G1_BODY(15, gB0,gB1,gB2,gB3, wload4(w1p,128, lane, wA0,wA1,wA2,wA3), )
    // kb=16 (dis/zero cols); next-weight prefetch chains into GEMM2's first quad
    G1_BODY(16, gA0,gA1,gA2,gA3, wload4(w2p, 0, lane, wA0,wA1,wA2,wA3), )
#undef G1_BODY

    // epilogue 1: bias + relu -> strip[pt][ch] bf16
    #pragma unroll
    for (int t = 0; t < 8; ++t) {
        const int chb = t * 16 + grp * 4;
        const float4 bv = *(const float4*)(b1 + chb);
        #pragma unroll
        for (int pt = 0; pt < 4; ++pt) {
            s16x4 pk;
            float v0 = acc[t][pt][0] + bv.x; pk[0] = (short)f2bf(v0 > 0.f ? v0 : 0.f);
            float v1 = acc[t][pt][1] + bv.y; pk[1] = (short)f2bf(v1 > 0.f ? v1 : 0.f);
            float v2 = acc[t][pt][2] + bv.z; pk[2] = (short)f2bf(v2 > 0.f ? v2 : 0.f);
            float v3 = acc[t][pt][3] + bv.w; pk[3] = (short)f2bf(v3 > 0.f ? v3 : 0.f);
            *(s16x4*)(strip + (pt * 16 + l15) * 136 + chb) = pk;
        }
    }

    // ================= GEMM2: [128 x 128] * [128 x 64] =================
    f32x4 acc2[8][4];
    #pragma unroll
    for (int t = 0; t < 8; ++t)
        #pragma unroll
        for (int pt = 0; pt < 4; ++pt) acc2[t][pt] = (f32x4){0.f, 0.f, 0.f, 0.f};

    dsread4(strip, 0, l15, grp8, gA0, gA1, gA2, gA3);

#define G23_BODY(WP, FR, S0,S1,S2,S3, ACC, WNEXT, DSNEXT)                   \
    wload4(WP, (FR) + 4, lane, wB0, wB1, wB2, wB3);                         \
    mfma_quad(ACC, 0, wA0, wA1, wA2, wA3, S0, S1, S2, S3);                  \
    WNEXT;                                                                  \
    DSNEXT;                                                                 \
    mfma_quad(ACC, 4, wB0, wB1, wB2, wB3, S0, S1, S2, S3);

    G23_BODY(w2p,  0, gA0,gA1,gA2,gA3, acc2, wload4(w2p,  8, lane, wA0,wA1,wA2,wA3), dsread4(strip, 1, l15, grp8, gB0,gB1,gB2,gB3))
    G23_BODY(w2p,  8, gB0,gB1,gB2,gB3, acc2, wload4(w2p, 16, lane, wA0,wA1,wA2,wA3), dsread4(strip, 2, l15, grp8, gA0,gA1,gA2,gA3))
    G23_BODY(w2p, 16, gA0,gA1,gA2,gA3, acc2, wload4(w2p, 24, lane, wA0,wA1,wA2,wA3), dsread4(strip, 3, l15, grp8, gB0,gB1,gB2,gB3))
    G23_BODY(w2p, 24, gB0,gB1,gB2,gB3, acc2, wload4(w3p,  0, lane, wA0,wA1,wA2,wA3), )

    // epilogue 2: bias + relu -> strip (H1 fully consumed; same-wave ordering)
    #pragma unroll
    for (int t = 0; t < 8; ++t) {
        const int chb = t * 16 + grp * 4;
        const float4 bv = *(const float4*)(b2 + chb);
        #pragma unroll
        for (int pt = 0; pt < 4; ++pt) {
            s16x4 pk;
            float v0 = acc2[t][pt][0] + bv.x; pk[0] = (short)f2bf(v0 > 0.f ? v0 : 0.f);
            float v1 = acc2[t][pt][1] + bv.y; pk[1] = (short)f2bf(v1 > 0.f ? v1 : 0.f);
            float v2 = acc2[t][pt][2] + bv.z; pk[2] = (short)f2bf(v2 > 0.f ? v2 : 0.f);
            float v3 = acc2[t][pt][3] + bv.w; pk[3] = (short)f2bf(v3 > 0.f ? v3 : 0.f);
            *(s16x4*)(strip + (pt * 16 + l15) * 136 + chb) = pk;
        }
    }

    // ================= GEMM3: [256 x 128] * [128 x 64], two halves =================
    #pragma unroll
    for (int half = 0; half < 2; ++half) {
        f32x4 acc3[8][4];
        #pragma unroll
        for (int t = 0; t < 8; ++t)
            #pragma unroll
            for (int pt = 0; pt < 4; ++pt) acc3[t][pt] = (f32x4){0.f, 0.f, 0.f, 0.f};

        dsread4(strip, 0, l15, grp8, gA0, gA1, gA2, gA3);
        if (half == 0) {
            G23_BODY(w3p,  0, gA0,gA1,gA2,gA3, acc3, wload4(w3p,  8, lane, wA0,wA1,wA2,wA3), dsread4(strip, 1, l15, grp8, gB0,gB1,gB2,gB3))
            G23_BODY(w3p,  8, gB0,gB1,gB2,gB3, acc3, wload4(w3p, 16, lane, wA0,wA1,wA2,wA3), dsread4(strip, 2, l15, grp8, gA0,gA1,gA2,gA3))
            G23_BODY(w3p, 16, gA0,gA1,gA2,gA3, acc3, wload4(w3p, 24, lane, wA0,wA1,wA2,wA3), dsread4(strip, 3, l15, grp8, gB0,gB1,gB2,gB3))
            G23_BODY(w3p, 24, gB0,gB1,gB2,gB3, acc3, wload4(w3p, 32, lane, wA0,wA1,wA2,wA3), )
        } else {
            G23_BODY(w3p, 32, gA0,gA1,gA2,gA3, acc3, wload4(w3p, 40, lane, wA0,wA1,wA2,wA3), dsread4(strip, 1, l15, grp8, gB0,gB1,gB2,gB3))
            G23_BODY(w3p, 40, gB0,gB1,gB2,gB3, acc3, wload4(w3p, 48, lane, wA0,wA1,wA2,wA3), dsread4(strip, 2, l15, grp8, gA0,gA1,gA2,gA3))
            G23_BODY(w3p, 48, gA0,gA1,gA2,gA3, acc3, wload4(w3p, 56, lane, wA0,wA1,wA2,wA3), dsread4(strip, 3, l15, grp8, gB0,gB1,gB2,gB3))
            G23_BODY(w3p, 56, gB0,gB1,gB2,gB3, acc3, , )
        }

        #pragma unroll
        for (int t = 0; t < 8; ++t) {
            const int chb = half * 128 + t * 16 + grp * 4;
            const float4 bv = *(const float4*)(b3 + chb);
            #pragma unroll
            for (int pt = 0; pt < 4; ++pt) {
                const int n = n0 + pt * 16 + l15;
                float* op = out + (((size_t)(b * 256 + chb)) << 14) + n;
                op[0]                  = acc3[t][pt][0] + bv.x;
                op[(size_t)1 << 14]    = acc3[t][pt][1] + bv.y;
                op[(size_t)2 << 14]    = acc3[t][pt][2] + bv.z;
                op[(size_t)3 << 14]    = acc3[t][pt][3] + bv.w;
            }
        }
    }
#undef G23_BODY
}

extern "C" void kernel_launch(void* const* d_in, const int* in_sizes, int n_in,
                              void* d_out, int out_size, void* d_ws, size_t ws_size,
                              hipStream_t stream)
{
    const float* feature = (const float*)d_in[0];
    const int*   idx     = (const int*)d_in[1];
    const float* dis     = (const float*)d_in[2];
    const float* W1      = (const float*)d_in[3];
    const float* b1      = (const float*)d_in[4];
    const float* W2      = (const float*)d_in[5];
    const float* b2      = (const float*)d_in[6];
    const float* W3      = (const float*)d_in[7];
    const float* b3      = (const float*)d_in[8];
    float* out = (float*)d_out;

    char* ws = (char*)d_ws;
    unsigned short* featT = (unsigned short*)ws;
    unsigned short* disB  = (unsigned short*)(ws + OFF_DISB);
    unsigned short* w1p   = (unsigned short*)(ws + OFF_W1B);
    unsigned short* w2p   = (unsigned short*)(ws + OFF_W2B);
    unsigned short* w3p   = (unsigned short*)(ws + OFF_W3B);

    hipLaunchKernelGGL(prep_misc, dim3(570), dim3(256), 0, stream,
                       dis, W1, W2, W3, disB, w1p, w2p, w3p);
    hipLaunchKernelGGL(prep_featT, dim3(512), dim3(256), 0, stream, feature, featT);
    hipLaunchKernelGGL(pointconv_main, dim3(2048), dim3(64), 0, stream,
                       featT, disB, idx, w1p, w2p, w3p, b1, b2, b3, out);
}